// Round 2
// baseline (1401.958 us; speedup 1.0000x reference)
//
#include <hip/hip_runtime.h>
#include <stdint.h>

// Problem constants (fixed by reference: B=4, S=2048, IN=4096, OUT=16384)
#define M_ROWS 8192     // B*S
#define N_COLS 16384    // OUT
#define K_ELEMS 4096    // IN
#define KW 128          // K in u32 words -- legacy popc path
#define LDS_STRIDE 20   // legacy popc path

// ============================================================================
// i8 MFMA path
// ============================================================================
typedef int i32x4  __attribute__((ext_vector_type(4)));
typedef int i32x16 __attribute__((ext_vector_type(16)));

typedef const __attribute__((address_space(1))) void* gptr_t;
typedef __attribute__((address_space(3))) void*       lptr_t;

__device__ __forceinline__ void gl16(const char* g, char* l) {
    // 16B-wide async global->LDS. LDS dest = wave-uniform base + lane*16.
    __builtin_amdgcn_global_load_lds((gptr_t)g, (lptr_t)l, 16, 0, 0);
}

// ---- sign converts: fp32 -> int8 in {+1 (0x01), -1 (0xFF)} -----------------
__global__ void conv_x_i8(const float4* __restrict__ x, uint32_t* __restrict__ o,
                          int n4) {
    int i = blockIdx.x * blockDim.x + threadIdx.x;
    int st = gridDim.x * blockDim.x;
    for (; i < n4; i += st) {
        float4 v = x[i];
        uint32_t b0 = (v.x >= 0.0f) ? 0x01u : 0xFFu;
        uint32_t b1 = (v.y >= 0.0f) ? 0x01u : 0xFFu;
        uint32_t b2 = (v.z >= 0.0f) ? 0x01u : 0xFFu;
        uint32_t b3 = (v.w >= 0.0f) ? 0x01u : 0xFFu;
        o[i] = b0 | (b1 << 8) | (b2 << 16) | (b3 << 24);
    }
}

__global__ void conv_w_i8(const float4* __restrict__ w, const float* __restrict__ thr,
                          uint32_t* __restrict__ o, int n4) {
    int i = blockIdx.x * blockDim.x + threadIdx.x;
    int st = gridDim.x * blockDim.x;
    for (; i < n4; i += st) {
        float t = thr[i >> 10];          // 1024 float4 per 4096-elem row
        float4 v = w[i];
        uint32_t b0 = (v.x - t >= 0.0f) ? 0x01u : 0xFFu;
        uint32_t b1 = (v.y - t >= 0.0f) ? 0x01u : 0xFFu;
        uint32_t b2 = (v.z - t >= 0.0f) ? 0x01u : 0xFFu;
        uint32_t b3 = (v.w - t >= 0.0f) ? 0x01u : 0xFFu;
        o[i] = b0 | (b1 << 8) | (b2 << 16) | (b3 << 24);
    }
}

// ---- i8 MFMA GEMM, 256^2 tile, 4-phase counted-vmcnt schedule ---------------
// out[m][n] = dot(A[m,:], B[n,:]) * scale.
// 8 waves (2M x 4N), 512 threads. Per wave: 128x64 output as 4x2
// mfma_i32_32x32x32_i8 accumulators. BK = 128 bytes/K-tile, NT = 32 tiles.
//
// LDS: [256 rows][8 x 16B slots], slot XOR-swizzled by (row&7) on BOTH sides:
//   - staging: linear LDS dest (global_load_lds requirement), global source
//     address pre-swizzled per-lane (slot_src = sl ^ rl)       [m173 pattern]
//   - reads: slot_read = ((p<<1)|hi) ^ (row&7), folded as base ^ (p<<5)
// => each quarter-wave hits each bank-quad <=2x: BW-minimal ds_read_b128.
//
// Schedule per K-tile t (buffers: cur = t&1):
//   [entry: tile t fully staged (vmcnt wait + barrier), A(t+1) in flight]
//   phase p=0..3: ds_read 6 frags(k-step p) from buf[cur];
//                 issue B-chunk p of tile t+1 -> buf[cur^1];
//                 barrier; setprio(1); 8 MFMA; setprio(0); barrier
//   [phase 3 end barrier: buf[cur] fully read by ALL waves -- each wave's
//    ds_reads are lgkmcnt-drained before its MFMAs, which precede the barrier]
//   issue A-chunks of tile t+2 -> buf[cur]   (safe: buffer just retired)
//   s_waitcnt vmcnt(4)  -> everything except the 4 newest (A(t+2)) landed,
//                          i.e. tile t+1 fully staged; barrier.
// vmcnt(0) only once, at t = NT-2 (tail). Never in steady state.
__launch_bounds__(512, 1)
__global__ void bgemm_i8_256(const char* __restrict__ A,   // [M][K] i8 +/-1
                             const char* __restrict__ B,   // [N][K] i8 +/-1
                             const float* __restrict__ shift,
                             float* __restrict__ out) {
    __shared__ __align__(16) char As[2][256 * 128];   // 32KB per buffer
    __shared__ __align__(16) char Bs[2][256 * 128];   // 128KB total

    const int tid  = threadIdx.x;
    const int lane = tid & 63;
    const int wid  = tid >> 6;          // 0..7
    const int wx   = wid & 3;           // N wave col (4 x 64)
    const int wy   = wid >> 2;          // M wave row (2 x 128)

    // T1: XCD-aware bijective swizzle (2048 blocks, 2048 % 8 == 0)
    const int bid = blockIdx.x;
    const int swz = (bid & 7) * 256 + (bid >> 3);
    const int bn  = (swz & 63) * 256;   // 64 N-tiles
    const int bm  = (swz >> 6) * 256;   // 32 M-tiles

    // scale: load + pin EARLY so its implicit vmcnt wait happens before any
    // staging load is issued (keeps the manual vmcnt(N) counts exact).
    const float sp    = shift[0];
    const float rr    = rintf(fminf(fmaxf(sp, -8.0f), 0.0f));  // round-half-even
    const float scale = exp2f(rr);
    asm volatile("" :: "v"(scale));

    // ---- staging geometry: one gl16 per wave per step; 8 steps/K-tile.
    // step q: 0..3 = A row-chunks (64 rows each), 4..7 = B row-chunks.
    // lane covers row rt = chunk*64 + wid*8 + (lane>>3), LDS slot sl = lane&7,
    // global slot = sl ^ (rt&7) = sl ^ rl  (chunk*64, wid*8 are 0 mod 8).
    const int rl = lane >> 3;
    const int sl = lane & 7;
    const char* gsrc[8];
    #pragma unroll
    for (int q = 0; q < 8; ++q) {
        int ch = q & 3;
        int rt = ch * 64 + wid * 8 + rl;
        const char* bp = (q < 4) ? A : B;
        int brow       = (q < 4) ? bm : bn;
        gsrc[q] = bp + (size_t)(brow + rt) * K_ELEMS + ((sl ^ rl) << 4);
    }
    const int ldst_w = wid * 1024;      // wave-uniform LDS offset within chunk

#define STAGE(q, buf, koff) do {                                             \
        char* _d = ((q) < 4) ? &As[(buf)][((q) & 3) * 8192 + ldst_w]         \
                             : &Bs[(buf)][((q) & 3) * 8192 + ldst_w];        \
        gl16(gsrc[q] + (koff), _d);                                          \
    } while (0)

    // ---- fragment read bases (k-step 0). Full slot for k-step p is
    // ((p<<1)|hi) ^ (row&7); realized as base ^ (p<<5) (slot bits 1..2 live
    // at byte-address bits 5..6; row*128 has no bits below 7).
    const int l31 = lane & 31, hi = lane >> 5;
    int aBase[4], bBase[2];
    #pragma unroll
    for (int mt = 0; mt < 4; ++mt) {
        int r = wy * 128 + mt * 32 + l31;
        aBase[mt] = r * 128 + ((hi ^ (r & 7)) << 4);
    }
    #pragma unroll
    for (int nt = 0; nt < 2; ++nt) {
        int r = wx * 64 + nt * 32 + l31;
        bBase[nt] = r * 128 + ((hi ^ (r & 7)) << 4);
    }

    i32x16 acc[4][2] = {};

    // ---- prologue: tile 0 (all 8 steps) -> buf0; tile 1 A-chunks -> buf1.
    STAGE(0, 0, 0); STAGE(1, 0, 0); STAGE(2, 0, 0); STAGE(3, 0, 0);
    STAGE(4, 0, 0); STAGE(5, 0, 0); STAGE(6, 0, 0); STAGE(7, 0, 0);
    STAGE(0, 1, 128); STAGE(1, 1, 128); STAGE(2, 1, 128); STAGE(3, 1, 128);
    asm volatile("s_waitcnt vmcnt(4)" ::: "memory");   // tile 0 landed
    __builtin_amdgcn_s_barrier();
    asm volatile("" ::: "memory");

    const int NT = K_ELEMS / 128;       // 32 K-tiles
    #pragma unroll 2
    for (int t = 0; t < NT; ++t) {
        const int cur = t & 1;
        const char* curA = &As[cur][0];
        const char* curB = &Bs[cur][0];
        const int koff1 = (t + 1) * 128;

        #pragma unroll
        for (int p = 0; p < 4; ++p) {
            i32x4 af[4], bf[2];
            #pragma unroll
            for (int mt = 0; mt < 4; ++mt)
                af[mt] = *(const i32x4*)(curA + (aBase[mt] ^ (p << 5)));
            #pragma unroll
            for (int nt = 0; nt < 2; ++nt)
                bf[nt] = *(const i32x4*)(curB + (bBase[nt] ^ (p << 5)));
            if (t + 1 < NT) {           // issue one B-chunk of tile t+1
                if      (p == 0) STAGE(4, cur ^ 1, koff1);
                else if (p == 1) STAGE(5, cur ^ 1, koff1);
                else if (p == 2) STAGE(6, cur ^ 1, koff1);
                else             STAGE(7, cur ^ 1, koff1);
            }
            asm volatile("" ::: "memory");
            __builtin_amdgcn_s_barrier();
            asm volatile("" ::: "memory");
            __builtin_amdgcn_s_setprio(1);
            #pragma unroll
            for (int mt = 0; mt < 4; ++mt)
                #pragma unroll
                for (int nt = 0; nt < 2; ++nt)
                    acc[mt][nt] = __builtin_amdgcn_mfma_i32_32x32x32_i8(
                        af[mt], bf[nt], acc[mt][nt], 0, 0, 0);
            __builtin_amdgcn_s_setprio(0);
            asm volatile("" ::: "memory");
            __builtin_amdgcn_s_barrier();
            asm volatile("" ::: "memory");
        }

        if (t + 2 < NT) {
            const int koff2 = (t + 2) * 128;
            STAGE(0, cur, koff2); STAGE(1, cur, koff2);
            STAGE(2, cur, koff2); STAGE(3, cur, koff2);
            asm volatile("s_waitcnt vmcnt(4)" ::: "memory");  // t+1 landed
            __builtin_amdgcn_s_barrier();
            asm volatile("" ::: "memory");
        } else if (t + 1 < NT) {        // tail: nothing left to prefetch
            asm volatile("s_waitcnt vmcnt(0)" ::: "memory");
            __builtin_amdgcn_s_barrier();
            asm volatile("" ::: "memory");
        }
    }
#undef STAGE

    // ---- epilogue: out = acc * 2^round(clip(shift,-8,0)), exact ----
    // C/D layout 32x32: col = lane&31, row = (reg&3) + 8*(reg>>2) + 4*(lane>>5)
    #pragma unroll
    for (int mt = 0; mt < 4; ++mt) {
        #pragma unroll
        for (int nt = 0; nt < 2; ++nt) {
            #pragma unroll
            for (int reg = 0; reg < 16; ++reg) {
                int row = bm + wy * 128 + mt * 32 + (reg & 3) + 8 * (reg >> 2) + 4 * hi;
                int col = bn + wx * 64 + nt * 32 + l31;
                out[(size_t)row * N_COLS + col] = scale * (float)acc[mt][nt][reg];
            }
        }
    }
}

// ============================================================================
// Legacy popc path (fallback if workspace < 96MB)
// ============================================================================
__global__ void pack_x_kernel(const float4* __restrict__ x,
                              uint64_t* __restrict__ out, int nwaves) {
    int lane = threadIdx.x & 63;
    int gw = (blockIdx.x * blockDim.x + threadIdx.x) >> 6;
    int stride = (gridDim.x * blockDim.x) >> 6;
    for (int w = gw; w < nwaves; w += stride) {
        float4 v = x[(size_t)w * 64 + lane];
        uint64_t m0 = __ballot(v.x < 0.0f);
        uint64_t m1 = __ballot(v.y < 0.0f);
        uint64_t m2 = __ballot(v.z < 0.0f);
        uint64_t m3 = __ballot(v.w < 0.0f);
        uint64_t sel = (lane == 0) ? m0 : (lane == 1) ? m1 : (lane == 2) ? m2 : m3;
        if (lane < 4) out[(size_t)w * 4 + lane] = sel;
    }
}

__global__ void pack_w_kernel(const float4* __restrict__ wgt,
                              const float* __restrict__ thr,
                              uint64_t* __restrict__ out, int nwaves) {
    int lane = threadIdx.x & 63;
    int gw = (blockIdx.x * blockDim.x + threadIdx.x) >> 6;
    int stride = (gridDim.x * blockDim.x) >> 6;
    for (int w = gw; w < nwaves; w += stride) {
        size_t f4 = (size_t)w * 64 + lane;
        float t = thr[f4 >> 10];
        float4 v = wgt[f4];
        uint64_t m0 = __ballot(v.x - t < 0.0f);
        uint64_t m1 = __ballot(v.y - t < 0.0f);
        uint64_t m2 = __ballot(v.z - t < 0.0f);
        uint64_t m3 = __ballot(v.w - t < 0.0f);
        uint64_t sel = (lane == 0) ? m0 : (lane == 1) ? m1 : (lane == 2) ? m2 : m3;
        if (lane < 4) out[(size_t)w * 4 + lane] = sel;
    }
}

__launch_bounds__(256, 2)
__global__ void bgemm_kernel(const uint32_t* __restrict__ A,
                             const uint32_t* __restrict__ B,
                             const float* __restrict__ shift,
                             float* __restrict__ out) {
    __shared__ uint32_t As[128 * LDS_STRIDE];
    __shared__ uint32_t Bs[128 * LDS_STRIDE];

    const int tid = threadIdx.x;
    const int tx = tid & 15;
    const int ty = tid >> 4;
    const int bm = blockIdx.y * 128;
    const int bn = blockIdx.x * 128;

    const int r0 = tid >> 2, g0 = tid & 3;
    const int r1 = (tid + 256) >> 2, g1 = tid & 3;

    uint32_t acc[8][8];
    #pragma unroll
    for (int i = 0; i < 8; ++i)
        #pragma unroll
        for (int j = 0; j < 8; ++j) acc[i][j] = 0u;

    uint4 pa0, pa1, pb0, pb1;
    pa0 = *(const uint4*)&A[(size_t)(bm + r0) * KW + 0 + g0 * 4];
    pa1 = *(const uint4*)&A[(size_t)(bm + r1) * KW + 0 + g1 * 4];
    pb0 = *(const uint4*)&B[(size_t)(bn + r0) * KW + 0 + g0 * 4];
    pb1 = *(const uint4*)&B[(size_t)(bn + r1) * KW + 0 + g1 * 4];

    for (int kb = 0; kb < KW; kb += 16) {
        *(uint4*)&As[r0 * LDS_STRIDE + g0 * 4] = pa0;
        *(uint4*)&As[r1 * LDS_STRIDE + g1 * 4] = pa1;
        *(uint4*)&Bs[r0 * LDS_STRIDE + g0 * 4] = pb0;
        *(uint4*)&Bs[r1 * LDS_STRIDE + g1 * 4] = pb1;
        __syncthreads();

        if (kb + 16 < KW) {
            int kn = kb + 16;
            pa0 = *(const uint4*)&A[(size_t)(bm + r0) * KW + kn + g0 * 4];
            pa1 = *(const uint4*)&A[(size_t)(bm + r1) * KW + kn + g1 * 4];
            pb0 = *(const uint4*)&B[(size_t)(bn + r0) * KW + kn + g0 * 4];
            pb1 = *(const uint4*)&B[(size_t)(bn + r1) * KW + kn + g1 * 4];
        }

        #pragma unroll
        for (int g = 0; g < 4; ++g) {
            uint4 b[8];
            #pragma unroll
            for (int c = 0; c < 8; ++c)
                b[c] = *(const uint4*)&Bs[(tx + 16 * c) * LDS_STRIDE + g * 4];
            #pragma unroll
            for (int r = 0; r < 8; ++r) {
                uint4 a = *(const uint4*)&As[(ty + 16 * r) * LDS_STRIDE + g * 4];
                #pragma unroll
                for (int c = 0; c < 8; ++c) {
                    acc[r][c] += __popc(a.x ^ b[c].x);
                    acc[r][c] += __popc(a.y ^ b[c].y);
                    acc[r][c] += __popc(a.z ^ b[c].z);
                    acc[r][c] += __popc(a.w ^ b[c].w);
                }
            }
        }
        __syncthreads();
    }

    float sp = shift[0];
    float rr = rintf(fminf(fmaxf(sp, -8.0f), 0.0f));
    float scale = exp2f(rr);
    float base = (float)K_ELEMS * scale;
    float m2s = -2.0f * scale;

    #pragma unroll
    for (int i = 0; i < 8; ++i) {
        size_t rowoff = (size_t)(bm + ty + 16 * i) * (size_t)N_COLS + (size_t)bn;
        #pragma unroll
        for (int j = 0; j < 8; ++j) {
            out[rowoff + tx + 16 * j] = fmaf(m2s, (float)acc[i][j], base);
        }
    }
}

// ============================================================================
extern "C" void kernel_launch(void* const* d_in, const int* in_sizes, int n_in,
                              void* d_out, int out_size, void* d_ws, size_t ws_size,
                              hipStream_t stream) {
    const float* x     = (const float*)d_in[0];   // [4,2048,4096] fp32
    const float* w     = (const float*)d_in[1];   // [16384,4096] fp32
    const float* thr   = (const float*)d_in[2];   // [16384,1] fp32
    const float* shift = (const float*)d_in[3];   // scalar fp32
    float* out = (float*)d_out;

    const size_t A_BYTES = (size_t)M_ROWS * K_ELEMS;   // 32 MB
    const size_t B_BYTES = (size_t)N_COLS * K_ELEMS;   // 64 MB

    if (ws_size >= A_BYTES + B_BYTES) {
        // ---- i8 MFMA path ----
        char* Ai8 = (char*)d_ws;
        char* Bi8 = Ai8 + A_BYTES;

        conv_x_i8<<<2048, 256, 0, stream>>>((const float4*)x, (uint32_t*)Ai8,
                                            (int)(A_BYTES / 4));
        conv_w_i8<<<2048, 256, 0, stream>>>((const float4*)w, thr, (uint32_t*)Bi8,
                                            (int)(B_BYTES / 4));

        // 2048 blocks of 512 threads: (16384/256) x (8192/256) tiles
        bgemm_i8_256<<<2048, 512, 0, stream>>>(Ai8, Bi8, shift, out);
    } else {
        // ---- legacy popc path (small workspace) ----
        uint32_t* Apk = (uint32_t*)d_ws;
        uint32_t* Bpk = Apk + (size_t)M_ROWS * KW;

        pack_x_kernel<<<2048, 256, 0, stream>>>((const float4*)x, (uint64_t*)Apk,
                                                (M_ROWS * K_ELEMS) / 256);
        pack_w_kernel<<<4096, 256, 0, stream>>>((const float4*)w, thr, (uint64_t*)Bpk,
                                                (N_COLS * K_ELEMS) / 256);

        dim3 grid(N_COLS / 128, M_ROWS / 128);
        bgemm_kernel<<<grid, 256, 0, stream>>>(Apk, Bpk, shift, out);
    }
}

// Round 3
// 1290.181 us; speedup vs baseline: 1.0866x; 1.0866x over previous
//
#include <hip/hip_runtime.h>
#include <stdint.h>

// Problem constants (fixed by reference: B=4, S=2048, IN=4096, OUT=16384)
#define M_ROWS 8192     // B*S
#define N_COLS 16384    // OUT
#define K_ELEMS 4096    // IN
#define KW 128          // K in u32 words -- legacy popc path
#define LDS_STRIDE 20   // legacy popc path

// ============================================================================
// i8 MFMA path
// ============================================================================
typedef int i32x4  __attribute__((ext_vector_type(4)));
typedef int i32x16 __attribute__((ext_vector_type(16)));

typedef const __attribute__((address_space(1))) void* gptr_t;
typedef __attribute__((address_space(3))) void*       lptr_t;

__device__ __forceinline__ void gl16(const char* g, char* l) {
    // 16B-wide async global->LDS. LDS dest = wave-uniform base + lane*16.
    __builtin_amdgcn_global_load_lds((gptr_t)g, (lptr_t)l, 16, 0, 0);
}

// ---- sign converts: fp32 -> int8 in {+1 (0x01), -1 (0xFF)} -----------------
__global__ void conv_x_i8(const float4* __restrict__ x, uint32_t* __restrict__ o,
                          int n4) {
    int i = blockIdx.x * blockDim.x + threadIdx.x;
    int st = gridDim.x * blockDim.x;
    for (; i < n4; i += st) {
        float4 v = x[i];
        uint32_t b0 = (v.x >= 0.0f) ? 0x01u : 0xFFu;
        uint32_t b1 = (v.y >= 0.0f) ? 0x01u : 0xFFu;
        uint32_t b2 = (v.z >= 0.0f) ? 0x01u : 0xFFu;
        uint32_t b3 = (v.w >= 0.0f) ? 0x01u : 0xFFu;
        o[i] = b0 | (b1 << 8) | (b2 << 16) | (b3 << 24);
    }
}

__global__ void conv_w_i8(const float4* __restrict__ w, const float* __restrict__ thr,
                          uint32_t* __restrict__ o, int n4) {
    int i = blockIdx.x * blockDim.x + threadIdx.x;
    int st = gridDim.x * blockDim.x;
    for (; i < n4; i += st) {
        float t = thr[i >> 10];          // 1024 float4 per 4096-elem row
        float4 v = w[i];
        uint32_t b0 = (v.x - t >= 0.0f) ? 0x01u : 0xFFu;
        uint32_t b1 = (v.y - t >= 0.0f) ? 0x01u : 0xFFu;
        uint32_t b2 = (v.z - t >= 0.0f) ? 0x01u : 0xFFu;
        uint32_t b3 = (v.w - t >= 0.0f) ? 0x01u : 0xFFu;
        o[i] = b0 | (b1 << 8) | (b2 << 16) | (b3 << 24);
    }
}

// ---- i8 MFMA GEMM, 256^2 tile, tile-deep pipeline, 2 barriers/K-tile --------
// out[m][n] = dot(A[m,:], B[n,:]) * scale.
// 8 waves (2M x 4N), 512 threads. Per wave: 128x64 output as 4x2
// mfma_i32_32x32x32_i8 accumulators. BK = 128 bytes/K-tile, NT = 32 tiles.
//
// LDS: [256 rows][8 x 16B slots], slot XOR-swizzled by (row&7) on BOTH sides:
//   - staging: linear LDS dest (global_load_lds requirement), global source
//     address pre-swizzled per-lane (slot_src = sl ^ rl)       [m173 pattern]
//   - reads: slot_read = ((p<<1)|hi) ^ (row&7), folded as base ^ (p<<5)
// (verified exact by the round-1/2 harness runs, absmax = 0)
//
// Schedule per K-tile t (buffers: cur = t&1):
//   STAGE all 8 chunks of tile t+1 -> buf[cur^1]   (full-tile-ahead prefetch:
//        tile-t's own loads were issued one full tile (~2400 cyc) ago, so the
//        vmcnt below never exposes HBM latency in steady state)
//   s_waitcnt vmcnt(8)   -> everything except the 8 newest (t+1) has landed,
//        i.e. tile t fully staged;   barrier  (all waves' waits done)
//   4 phases of {6 ds_read_b128 ; 8 MFMA} with NO barriers: the compiler's
//        fine-grained lgkmcnt lets phase p+1 reads run under phase p MFMAs,
//        overlapping the CU-shared LDS pipe with the per-SIMD matrix pipes.
//   barrier  -> every wave's reads of buf[cur] are register-drained (each
//        read feeds an MFMA before this point), so tile t+1 may overwrite
//        buf[cur] after this barrier.  vmcnt(0) only in the tail tile.
__launch_bounds__(512, 1)
__global__ void bgemm_i8_256(const char* __restrict__ A,   // [M][K] i8 +/-1
                             const char* __restrict__ B,   // [N][K] i8 +/-1
                             const float* __restrict__ shift,
                             float* __restrict__ out) {
    __shared__ __align__(16) char As[2][256 * 128];   // 32KB per buffer
    __shared__ __align__(16) char Bs[2][256 * 128];   // 128KB total

    const int tid  = threadIdx.x;
    const int lane = tid & 63;
    const int wid  = tid >> 6;          // 0..7
    const int wx   = wid & 3;           // N wave col (4 x 64)
    const int wy   = wid >> 2;          // M wave row (2 x 128)

    // T1: XCD-aware bijective swizzle (2048 blocks, 2048 % 8 == 0)
    const int bid = blockIdx.x;
    const int swz = (bid & 7) * 256 + (bid >> 3);
    const int bn  = (swz & 63) * 256;   // 64 N-tiles
    const int bm  = (swz >> 6) * 256;   // 32 M-tiles

    // scale: materialize early (s_load -> lgkmcnt; does not disturb vmcnt).
    const float sp    = shift[0];
    const float rr    = rintf(fminf(fmaxf(sp, -8.0f), 0.0f));  // round-half-even
    const float scale = exp2f(rr);
    asm volatile("" :: "v"(scale));

    // ---- staging geometry: one gl16 per wave per chunk; 8 chunks/K-tile.
    // chunk q: 0..3 = A row-chunks (64 rows each), 4..7 = B row-chunks.
    // lane covers row rt = chunk*64 + wid*8 + (lane>>3), LDS slot sl = lane&7,
    // global slot = sl ^ (rt&7) = sl ^ rl  (chunk*64, wid*8 are 0 mod 8).
    const int rl = lane >> 3;
    const int sl = lane & 7;
    const char* gsrc[8];
    #pragma unroll
    for (int q = 0; q < 8; ++q) {
        int ch = q & 3;
        int rt = ch * 64 + wid * 8 + rl;
        const char* bp = (q < 4) ? A : B;
        int brow       = (q < 4) ? bm : bn;
        gsrc[q] = bp + (size_t)(brow + rt) * K_ELEMS + ((sl ^ rl) << 4);
    }
    const int ldst_w = wid * 1024;      // wave-uniform LDS offset within chunk

#define STAGE(q, buf, koff) do {                                             \
        char* _d = ((q) < 4) ? &As[(buf)][((q) & 3) * 8192 + ldst_w]         \
                             : &Bs[(buf)][((q) & 3) * 8192 + ldst_w];        \
        gl16(gsrc[q] + (koff), _d);                                          \
    } while (0)

    // ---- fragment read bases (k-step 0). Full slot for k-step p is
    // ((p<<1)|hi) ^ (row&7); realized as base ^ (p<<5) (slot bits 1..2 live
    // at byte-address bits 5..6; row*128 has no bits below 7).
    const int l31 = lane & 31, hi = lane >> 5;
    int aBase[4], bBase[2];
    #pragma unroll
    for (int mt = 0; mt < 4; ++mt) {
        int r = wy * 128 + mt * 32 + l31;
        aBase[mt] = r * 128 + ((hi ^ (r & 7)) << 4);
    }
    #pragma unroll
    for (int nt = 0; nt < 2; ++nt) {
        int r = wx * 64 + nt * 32 + l31;
        bBase[nt] = r * 128 + ((hi ^ (r & 7)) << 4);
    }

    i32x16 acc[4][2] = {};

    // ---- prologue: tile 0 (all 8 chunks) -> buf0.
    STAGE(0, 0, 0); STAGE(1, 0, 0); STAGE(2, 0, 0); STAGE(3, 0, 0);
    STAGE(4, 0, 0); STAGE(5, 0, 0); STAGE(6, 0, 0); STAGE(7, 0, 0);

    const int NT = K_ELEMS / 128;       // 32 K-tiles
    #pragma unroll 2
    for (int t = 0; t < NT; ++t) {
        const int cur = t & 1;
        const char* curA = &As[cur][0];
        const char* curB = &Bs[cur][0];

        if (t + 1 < NT) {
            const int koff1 = (t + 1) * 128;
            STAGE(0, cur ^ 1, koff1); STAGE(1, cur ^ 1, koff1);
            STAGE(2, cur ^ 1, koff1); STAGE(3, cur ^ 1, koff1);
            STAGE(4, cur ^ 1, koff1); STAGE(5, cur ^ 1, koff1);
            STAGE(6, cur ^ 1, koff1); STAGE(7, cur ^ 1, koff1);
            // tile-t loads (issued one full tile ago) landed; t+1's 8 in flight
            asm volatile("s_waitcnt vmcnt(8)" ::: "memory");
        } else {
            asm volatile("s_waitcnt vmcnt(0)" ::: "memory");
        }
        __builtin_amdgcn_s_barrier();
        asm volatile("" ::: "memory");

        __builtin_amdgcn_s_setprio(1);
        #pragma unroll
        for (int p = 0; p < 4; ++p) {
            i32x4 af[4], bf[2];
            #pragma unroll
            for (int mt = 0; mt < 4; ++mt)
                af[mt] = *(const i32x4*)(curA + (aBase[mt] ^ (p << 5)));
            #pragma unroll
            for (int nt = 0; nt < 2; ++nt)
                bf[nt] = *(const i32x4*)(curB + (bBase[nt] ^ (p << 5)));
            #pragma unroll
            for (int mt = 0; mt < 4; ++mt)
                #pragma unroll
                for (int nt = 0; nt < 2; ++nt)
                    acc[mt][nt] = __builtin_amdgcn_mfma_i32_32x32x32_i8(
                        af[mt], bf[nt], acc[mt][nt], 0, 0, 0);
        }
        __builtin_amdgcn_s_setprio(0);
        asm volatile("" ::: "memory");
        // all reads of buf[cur] are drained into registers (each fed an MFMA
        // above); after this barrier tile t+1's iteration may overwrite it.
        __builtin_amdgcn_s_barrier();
        asm volatile("" ::: "memory");
    }
#undef STAGE

    // ---- epilogue: out = acc * 2^round(clip(shift,-8,0)), exact ----
    // C/D layout 32x32: col = lane&31, row = (reg&3) + 8*(reg>>2) + 4*(lane>>5)
    #pragma unroll
    for (int mt = 0; mt < 4; ++mt) {
        #pragma unroll
        for (int nt = 0; nt < 2; ++nt) {
            #pragma unroll
            for (int reg = 0; reg < 16; ++reg) {
                int row = bm + wy * 128 + mt * 32 + (reg & 3) + 8 * (reg >> 2) + 4 * hi;
                int col = bn + wx * 64 + nt * 32 + l31;
                out[(size_t)row * N_COLS + col] = scale * (float)acc[mt][nt][reg];
            }
        }
    }
}

// ============================================================================
// Legacy popc path (fallback if workspace < 96MB)
// ============================================================================
__global__ void pack_x_kernel(const float4* __restrict__ x,
                              uint64_t* __restrict__ out, int nwaves) {
    int lane = threadIdx.x & 63;
    int gw = (blockIdx.x * blockDim.x + threadIdx.x) >> 6;
    int stride = (gridDim.x * blockDim.x) >> 6;
    for (int w = gw; w < nwaves; w += stride) {
        float4 v = x[(size_t)w * 64 + lane];
        uint64_t m0 = __ballot(v.x < 0.0f);
        uint64_t m1 = __ballot(v.y < 0.0f);
        uint64_t m2 = __ballot(v.z < 0.0f);
        uint64_t m3 = __ballot(v.w < 0.0f);
        uint64_t sel = (lane == 0) ? m0 : (lane == 1) ? m1 : (lane == 2) ? m2 : m3;
        if (lane < 4) out[(size_t)w * 4 + lane] = sel;
    }
}

__global__ void pack_w_kernel(const float4* __restrict__ wgt,
                              const float* __restrict__ thr,
                              uint64_t* __restrict__ out, int nwaves) {
    int lane = threadIdx.x & 63;
    int gw = (blockIdx.x * blockDim.x + threadIdx.x) >> 6;
    int stride = (gridDim.x * blockDim.x) >> 6;
    for (int w = gw; w < nwaves; w += stride) {
        size_t f4 = (size_t)w * 64 + lane;
        float t = thr[f4 >> 10];
        float4 v = wgt[f4];
        uint64_t m0 = __ballot(v.x - t < 0.0f);
        uint64_t m1 = __ballot(v.y - t < 0.0f);
        uint64_t m2 = __ballot(v.z - t < 0.0f);
        uint64_t m3 = __ballot(v.w - t < 0.0f);
        uint64_t sel = (lane == 0) ? m0 : (lane == 1) ? m1 : (lane == 2) ? m2 : m3;
        if (lane < 4) out[(size_t)w * 4 + lane] = sel;
    }
}

__launch_bounds__(256, 2)
__global__ void bgemm_kernel(const uint32_t* __restrict__ A,
                             const uint32_t* __restrict__ B,
                             const float* __restrict__ shift,
                             float* __restrict__ out) {
    __shared__ uint32_t As[128 * LDS_STRIDE];
    __shared__ uint32_t Bs[128 * LDS_STRIDE];

    const int tid = threadIdx.x;
    const int tx = tid & 15;
    const int ty = tid >> 4;
    const int bm = blockIdx.y * 128;
    const int bn = blockIdx.x * 128;

    const int r0 = tid >> 2, g0 = tid & 3;
    const int r1 = (tid + 256) >> 2, g1 = tid & 3;

    uint32_t acc[8][8];
    #pragma unroll
    for (int i = 0; i < 8; ++i)
        #pragma unroll
        for (int j = 0; j < 8; ++j) acc[i][j] = 0u;

    uint4 pa0, pa1, pb0, pb1;
    pa0 = *(const uint4*)&A[(size_t)(bm + r0) * KW + 0 + g0 * 4];
    pa1 = *(const uint4*)&A[(size_t)(bm + r1) * KW + 0 + g1 * 4];
    pb0 = *(const uint4*)&B[(size_t)(bn + r0) * KW + 0 + g0 * 4];
    pb1 = *(const uint4*)&B[(size_t)(bn + r1) * KW + 0 + g1 * 4];

    for (int kb = 0; kb < KW; kb += 16) {
        *(uint4*)&As[r0 * LDS_STRIDE + g0 * 4] = pa0;
        *(uint4*)&As[r1 * LDS_STRIDE + g1 * 4] = pa1;
        *(uint4*)&Bs[r0 * LDS_STRIDE + g0 * 4] = pb0;
        *(uint4*)&Bs[r1 * LDS_STRIDE + g1 * 4] = pb1;
        __syncthreads();

        if (kb + 16 < KW) {
            int kn = kb + 16;
            pa0 = *(const uint4*)&A[(size_t)(bm + r0) * KW + kn + g0 * 4];
            pa1 = *(const uint4*)&A[(size_t)(bm + r1) * KW + kn + g1 * 4];
            pb0 = *(const uint4*)&B[(size_t)(bn + r0) * KW + kn + g0 * 4];
            pb1 = *(const uint4*)&B[(size_t)(bn + r1) * KW + kn + g1 * 4];
        }

        #pragma unroll
        for (int g = 0; g < 4; ++g) {
            uint4 b[8];
            #pragma unroll
            for (int c = 0; c < 8; ++c)
                b[c] = *(const uint4*)&Bs[(tx + 16 * c) * LDS_STRIDE + g * 4];
            #pragma unroll
            for (int r = 0; r < 8; ++r) {
                uint4 a = *(const uint4*)&As[(ty + 16 * r) * LDS_STRIDE + g * 4];
                #pragma unroll
                for (int c = 0; c < 8; ++c) {
                    acc[r][c] += __popc(a.x ^ b[c].x);
                    acc[r][c] += __popc(a.y ^ b[c].y);
                    acc[r][c] += __popc(a.z ^ b[c].z);
                    acc[r][c] += __popc(a.w ^ b[c].w);
                }
            }
        }
        __syncthreads();
    }

    float sp = shift[0];
    float rr = rintf(fminf(fmaxf(sp, -8.0f), 0.0f));
    float scale = exp2f(rr);
    float base = (float)K_ELEMS * scale;
    float m2s = -2.0f * scale;

    #pragma unroll
    for (int i = 0; i < 8; ++i) {
        size_t rowoff = (size_t)(bm + ty + 16 * i) * (size_t)N_COLS + (size_t)bn;
        #pragma unroll
        for (int j = 0; j < 8; ++j) {
            out[rowoff + tx + 16 * j] = fmaf(m2s, (float)acc[i][j], base);
        }
    }
}

// ============================================================================
extern "C" void kernel_launch(void* const* d_in, const int* in_sizes, int n_in,
                              void* d_out, int out_size, void* d_ws, size_t ws_size,
                              hipStream_t stream) {
    const float* x     = (const float*)d_in[0];   // [4,2048,4096] fp32
    const float* w     = (const float*)d_in[1];   // [16384,4096] fp32
    const float* thr   = (const float*)d_in[2];   // [16384,1] fp32
    const float* shift = (const float*)d_in[3];   // scalar fp32
    float* out = (float*)d_out;

    const size_t A_BYTES = (size_t)M_ROWS * K_ELEMS;   // 32 MB
    const size_t B_BYTES = (size_t)N_COLS * K_ELEMS;   // 64 MB

    if (ws_size >= A_BYTES + B_BYTES) {
        // ---- i8 MFMA path ----
        char* Ai8 = (char*)d_ws;
        char* Bi8 = Ai8 + A_BYTES;

        conv_x_i8<<<2048, 256, 0, stream>>>((const float4*)x, (uint32_t*)Ai8,
                                            (int)(A_BYTES / 4));
        conv_w_i8<<<2048, 256, 0, stream>>>((const float4*)w, thr, (uint32_t*)Bi8,
                                            (int)(B_BYTES / 4));

        // 2048 blocks of 512 threads: (16384/256) x (8192/256) tiles
        bgemm_i8_256<<<2048, 512, 0, stream>>>(Ai8, Bi8, shift, out);
    } else {
        // ---- legacy popc path (small workspace) ----
        uint32_t* Apk = (uint32_t*)d_ws;
        uint32_t* Bpk = Apk + (size_t)M_ROWS * KW;

        pack_x_kernel<<<2048, 256, 0, stream>>>((const float4*)x, (uint64_t*)Apk,
                                                (M_ROWS * K_ELEMS) / 256);
        pack_w_kernel<<<4096, 256, 0, stream>>>((const float4*)w, thr, (uint64_t*)Bpk,
                                                (N_COLS * K_ELEMS) / 256);

        dim3 grid(N_COLS / 128, M_ROWS / 128);
        bgemm_kernel<<<grid, 256, 0, stream>>>(Apk, Bpk, shift, out);
    }
}